// Round 10
// baseline (460.628 us; speedup 1.0000x reference)
//
#include <hip/hip_runtime.h>

typedef unsigned long long u64;
typedef float f32x4 __attribute__((ext_vector_type(4)));

#define THR 0.5f

// Convert one cxcywh box to ltrb + area, with FP contraction OFF so every op
// matches numpy's rn-per-op semantics bit-exactly (needed for the NMS >= 0.5
// predicate; a fused cx - 0.5*w -> fma differs in the last ulp).
__device__ __forceinline__ void conv_box(const float4 b, float& l, float& t,
                                         float& r, float& bo, float& a) {
  #pragma clang fp contract(off)
  float hw = 0.5f * b.z;
  float hh = 0.5f * b.w;
  l = b.x - hw;
  t = b.y - hh;
  r = b.x + hw;
  bo = b.y + hh;
  a = (r - l) * (bo - t);
}

__global__ void k_zero(int* __restrict__ rank, int n) {
  int i = blockIdx.x * blockDim.x + threadIdx.x;
  if (i < n) rank[i] = 0;
}

// Stable descending rank == stable argsort(-scores) position. j-chunked over
// blockIdx.y for parallelism.
__global__ void k_rank(const float* __restrict__ scores, int* __restrict__ rank,
                       int n, int jchunk) {
  int i = blockIdx.x * blockDim.x + threadIdx.x;
  if (i >= n) return;
  float si = scores[i];
  int j0 = blockIdx.y * jchunk;
  int j1 = min(j0 + jchunk, n);
  int c = 0;
  for (int j = j0; j < j1; ++j) {
    float sj = scores[j];
    c += ((sj > si) || (sj == si && j < i)) ? 1 : 0;
  }
  if (c) atomicAdd(rank + i, c);
}

__global__ void k_scatter(const float4* __restrict__ boxes, const int* __restrict__ rank,
                          float* __restrict__ sl, float* __restrict__ st,
                          float* __restrict__ sr, float* __restrict__ sb,
                          float* __restrict__ sa, int* __restrict__ sidx, int n) {
  int i = blockIdx.x * blockDim.x + threadIdx.x;
  if (i >= n) return;
  float l, t, r, b, a;
  conv_box(boxes[i], l, t, r, b, a);
  int k = rank[i];
  sl[k] = l; st[k] = t; sr[k] = r; sb[k] = b; sa[k] = a; sidx[k] = i;
}

// mask[k][w] bit b (j = w*64+b) set iff j>k, j<n, iou_nms(k,j) >= 0.5.
// Emits diag (diagonal 64x64 block) + band1/band2 (1st/2nd superdiagonal
// words) for the scan's depth-2 band. Reference does NOT clamp the
// intersection on the NMS path — replicate exactly.
__device__ __forceinline__ void mask_body(
    const float* __restrict__ sl, const float* __restrict__ st,
    const float* __restrict__ sr, const float* __restrict__ sb,
    const float* __restrict__ sa,
    u64* __restrict__ mask, u64* __restrict__ diag,
    u64* __restrict__ band1, u64* __restrict__ band2,
    int n, int wstride, int bx, int by) {
  #pragma clang fp contract(off)
  int k = bx * 256 + threadIdx.x;
  if (k >= n) return;
  int w = by;
  int jbase = w << 6;
  u64 word = 0;
  if (jbase + 63 > k) {
    float l = sl[k], t = st[k], r = sr[k], b = sb[k], a = sa[k];
    int jend = min(jbase + 64, n);
    for (int j = max(jbase, k + 1); j < jend; ++j) {
      float lmax = fmaxf(l, sl[j]);
      float tmax = fmaxf(t, st[j]);
      float rmin = fminf(r, sr[j]);
      float bmin = fminf(b, sb[j]);
      float wd = rmin - lmax;
      float hd = bmin - tmax;
      float inter = wd * hd;               // no clamp (matches reference NMS path)
      float denom = (a + sa[j]) - inter;
      float q = inter / denom;             // IEEE f32 div
      if (q >= THR) word |= 1ull << (j - jbase);
    }
  }
  mask[(size_t)k * wstride + w] = word;
  int kg = k >> 6;
  if (kg == w) diag[k] = word;
  if (w == kg + 1) band1[k] = word;
  if (w == kg + 2) band2[k] = word;
}

__global__ void k_mask(const float* __restrict__ sl, const float* __restrict__ st,
                       const float* __restrict__ sr, const float* __restrict__ sb,
                       const float* __restrict__ sa,
                       u64* __restrict__ mask, u64* __restrict__ diag,
                       u64* __restrict__ band1, u64* __restrict__ band2,
                       int n, int wstride) {
  mask_body(sl, st, sr, sb, sa, mask, diag, band1, band2, n, wstride,
            blockIdx.x, blockIdx.y);
}

// Canonical GCN wave64 OR-reduce via DPP (VALU) instead of dependent bpermutes.
__device__ __forceinline__ u64 wave_or_u64(u64 v) {
  unsigned lo = (unsigned)v, hi = (unsigned)(v >> 32);
#define DPP_OR(x, ctrl, rmask) \
  x |= (unsigned)__builtin_amdgcn_update_dpp(0, (int)(x), ctrl, rmask, 0xF, true)
  DPP_OR(lo, 0x111, 0xF); DPP_OR(hi, 0x111, 0xF);   // row_shr:1
  DPP_OR(lo, 0x112, 0xF); DPP_OR(hi, 0x112, 0xF);   // row_shr:2
  DPP_OR(lo, 0x114, 0xF); DPP_OR(hi, 0x114, 0xF);   // row_shr:4
  DPP_OR(lo, 0x118, 0xF); DPP_OR(hi, 0x118, 0xF);   // row_shr:8
  DPP_OR(lo, 0x142, 0xA); DPP_OR(hi, 0x142, 0xA);   // row_bcast:15 rows 1,3
  DPP_OR(lo, 0x143, 0xC); DPP_OR(hi, 0x143, 0xC);   // row_bcast:31 rows 2,3
#undef DPP_OR
  unsigned flo = (unsigned)__builtin_amdgcn_readlane((int)lo, 63);
  unsigned fhi = (unsigned)__builtin_amdgcn_readlane((int)hi, 63);
  return ((u64)fhi << 32) | flo;
}

// ---------------------------------------------------------------------------
// Greedy serial NMS scan — 256 threads, runs SOLO.
//  wave 0: register-double-buffered serial chain; depth-2 running band
//    (R1/R2 registers, DPP reduces over band1/band2) so the lazy fold only
//    owes words w-h > 2 — fold of group g-2 runs during group g.
//  waves 1-3: fold of group g-2's kept rows into rem[w], w>g: 32 NAMED
//    in-flight loads per batch (round-8 bug: VGPR=36 showed the compiler
//    kept only ~8 loads in flight -> serialized L3 round-trips).
// ---------------------------------------------------------------------------
__device__ __forceinline__ void scan_body8(
    const u64* __restrict__ mask, const u64* __restrict__ diag,
    const u64* __restrict__ band1, const u64* __restrict__ band2,
    const int* __restrict__ sidx, float* __restrict__ keep,
    int n, int wstride,
    u64* rem, u64* dsh, u64* bsh1, u64* bsh2, u64* kwords,
    int (*kept)[64], int* nk_sh) {
  int t = threadIdx.x, wv = t >> 6, lane = t & 63;
  int ng = (n + 63) >> 6;
  rem[t] = 0;
  if (t < 3) nk_sh[t] = 0;
  u64 R1 = 0, R2 = 0;
  u64 x0 = 0, x1 = 0, x2 = 0, x3 = 0, x4 = 0, x5 = 0, x6 = 0, x7 = 0;
  const ulonglong2* d2 = (const ulonglong2*)dsh;
  if (wv == 0) {
    dsh[lane] = diag[lane];
    bsh1[lane] = band1[lane];
    bsh2[lane] = band2[lane];
    ulonglong2 p0 = d2[0], p1 = d2[1], p2 = d2[2], p3 = d2[3];
    x0 = p0.x; x1 = p0.y; x2 = p1.x; x3 = p1.y;
    x4 = p2.x; x5 = p2.y; x6 = p3.x; x7 = p3.y;
  }
  __syncthreads();
  for (int g = 0; g < ng; ++g) {
    int base = g << 6;
    if (wv == 0) {
      // prefetch next group's diag/band (hides under the chain)
      int nxt = base + 64 + lane;
      bool hn = (g + 1 < ng);
      u64 dnext = hn ? diag[nxt] : 0;
      u64 b1next = hn ? band1[nxt] : 0;
      u64 b2next = hn ? band2[nxt] : 0;
      u64 b1v = bsh1[lane], b2v = bsh2[lane];   // off-chain LDS reads
      u64 s = rem[g] | R1;       // R1 = groups g-2,g-1 contributions to word g
      int valid = n - base;
      if (valid < 64) s |= (~0ull) << valid;  // nonexistent boxes = suppressed
      u64 kw = 0;
      u64 y0, y1, y2, y3, y4, y5, y6, y7;
#define LDC(a0,a1,a2,a3,a4,a5,a6,a7, c) { \
      ulonglong2 q0 = d2[4*(c)], q1 = d2[4*(c)+1], q2 = d2[4*(c)+2], q3 = d2[4*(c)+3]; \
      a0 = q0.x; a1 = q0.y; a2 = q1.x; a3 = q1.y; a4 = q2.x; a5 = q2.y; a6 = q3.x; a7 = q3.y; }
#define STEP(BB, EQ) if (!((s >> (BB)) & 1ull)) { kw |= 1ull << (BB); s |= EQ; }
#define CHUNK(b0v, a0,a1,a2,a3,a4,a5,a6,a7) \
      if ((unsigned)((s >> (b0v)) & 0xFFull) != 0xFFu) { \
        STEP(b0v+0, a0) STEP(b0v+1, a1) STEP(b0v+2, a2) STEP(b0v+3, a3) \
        STEP(b0v+4, a4) STEP(b0v+5, a5) STEP(b0v+6, a6) STEP(b0v+7, a7) }
      LDC(y0,y1,y2,y3,y4,y5,y6,y7, 1); CHUNK(0,  x0,x1,x2,x3,x4,x5,x6,x7);
      LDC(x0,x1,x2,x3,x4,x5,x6,x7, 2); CHUNK(8,  y0,y1,y2,y3,y4,y5,y6,y7);
      LDC(y0,y1,y2,y3,y4,y5,y6,y7, 3); CHUNK(16, x0,x1,x2,x3,x4,x5,x6,x7);
      LDC(x0,x1,x2,x3,x4,x5,x6,x7, 4); CHUNK(24, y0,y1,y2,y3,y4,y5,y6,y7);
      LDC(y0,y1,y2,y3,y4,y5,y6,y7, 5); CHUNK(32, x0,x1,x2,x3,x4,x5,x6,x7);
      LDC(x0,x1,x2,x3,x4,x5,x6,x7, 6); CHUNK(40, y0,y1,y2,y3,y4,y5,y6,y7);
      LDC(y0,y1,y2,y3,y4,y5,y6,y7, 7); CHUNK(48, x0,x1,x2,x3,x4,x5,x6,x7);
                                       CHUNK(56, y0,y1,y2,y3,y4,y5,y6,y7);
#undef CHUNK
#undef STEP
#undef LDC
      if (lane == 0) kwords[g] = kw;
      u64 c1 = 0, c2 = 0;
      if (kw) {
        // compact kept bits -> triple-buffered LDS list, pad to x32 with 0
        int nk = __popcll(kw);
        if ((kw >> lane) & 1ull) {
          int pos = __popcll(kw & ((1ull << lane) - 1ull));
          kept[g % 3][pos] = lane;
        }
        int npad = (nk + 31) & ~31;
        if (lane >= nk && lane < npad) kept[g % 3][lane] = 0;
        if (lane == 0) nk_sh[g % 3] = nk;
        u64 m = (u64)0 - ((kw >> lane) & 1ull);
        c1 = wave_or_u64(b1v & m);
        c2 = wave_or_u64(b2v & m);
      } else {
        if (lane == 0) nk_sh[g % 3] = 0;
      }
      R1 = R2 | c1;
      R2 = c2;
      dsh[lane] = dnext;     // after all chain reads (wave-ordered LDS)
      bsh1[lane] = b1next;
      bsh2[lane] = b2next;
      // pre-read chunk 0 of the NEXT group before the barrier
      ulonglong2 p0 = d2[0], p1 = d2[1], p2 = d2[2], p3 = d2[3];
      x0 = p0.x; x1 = p0.y; x2 = p1.x; x3 = p1.y;
      x4 = p2.x; x5 = p2.y; x6 = p3.x; x7 = p3.y;
    } else {
      // fold group g-2's kept rows into rem[w], w > g (words w-h<=2 are
      // covered by the R1/R2 band). 32 named loads in flight per batch.
      int w = t - 64;
      int gp = g - 2;
      if (gp >= 0 && w > g && w < ng) {
        int nkp = nk_sh[gp % 3];
        if (nkp) {
          const int* kp = kept[gp % 3];
          int basep = gp << 6;
          u64 acc = 0;
          for (int i = 0; i < nkp; i += 32) {
#define LD1(q) u64 v##q = mask[(size_t)(basep + kp[i + q]) * wstride + w];
            LD1(0)  LD1(1)  LD1(2)  LD1(3)  LD1(4)  LD1(5)  LD1(6)  LD1(7)
            LD1(8)  LD1(9)  LD1(10) LD1(11) LD1(12) LD1(13) LD1(14) LD1(15)
            LD1(16) LD1(17) LD1(18) LD1(19) LD1(20) LD1(21) LD1(22) LD1(23)
            LD1(24) LD1(25) LD1(26) LD1(27) LD1(28) LD1(29) LD1(30) LD1(31)
#undef LD1
#define ACC(q) if (i + q < nkp) acc |= v##q;
            ACC(0)  ACC(1)  ACC(2)  ACC(3)  ACC(4)  ACC(5)  ACC(6)  ACC(7)
            ACC(8)  ACC(9)  ACC(10) ACC(11) ACC(12) ACC(13) ACC(14) ACC(15)
            ACC(16) ACC(17) ACC(18) ACC(19) ACC(20) ACC(21) ACC(22) ACC(23)
            ACC(24) ACC(25) ACC(26) ACC(27) ACC(28) ACC(29) ACC(30) ACC(31)
#undef ACC
          }
          rem[w] |= acc;
        }
      }
    }
    __syncthreads();
  }
  // final scatter: sorted keep bits -> original order (parallel, coalesced sidx)
  for (int k = t; k < n; k += 256) {
    u64 kwv = kwords[k >> 6];
    keep[sidx[k]] = ((kwv >> (k & 63)) & 1ull) ? 1.0f : 0.0f;
  }
}

__global__ __launch_bounds__(256, 1) void k_scan2(const u64* __restrict__ mask,
                                                  const u64* __restrict__ diag,
                                                  const u64* __restrict__ band1,
                                                  const u64* __restrict__ band2,
                                                  const int* __restrict__ sidx,
                                                  float* __restrict__ keep,
                                                  int n, int wstride) {
  __shared__ u64 rem[256];
  __shared__ __align__(16) u64 dsh[64];
  __shared__ u64 bsh1[64];
  __shared__ u64 bsh2[64];
  __shared__ u64 kwords[160];
  __shared__ int kept[3][64];
  __shared__ int nk_sh[3];
  scan_body8(mask, diag, band1, band2, sidx, keep, n, wstride,
             rem, dsh, bsh1, bsh2, kwords, kept, nk_sh);
}

// Pairwise IoU, original order, WITH clamp. Loose 2e-2 threshold -> fast rcp.
__device__ __forceinline__ float iou_one(float li, float ti, float ri, float bi, float ai,
                                         float lj, float tj, float rj, float bj, float aj) {
  float lmax = fmaxf(li, lj);
  float tmax = fmaxf(ti, tj);
  float rmin = fminf(ri, rj);
  float bmin = fminf(bi, bj);
  float w = fmaxf(rmin - lmax, 0.0f);
  float h = fmaxf(bmin - tmax, 0.0f);
  float inter = w * h;
  float denom = (ai + aj) - inter;
  return inter * __builtin_amdgcn_rcpf(denom);
}

__device__ __forceinline__ void iou_body(const float4* __restrict__ boxes,
                                         float* __restrict__ out,
                                         int n, int rpb, int bx, int by) {
  int nj4 = (n + 3) >> 2;
  int j4 = bx * 256 + threadIdx.x;
  if (j4 >= nj4) return;
  int j = j4 << 2;
  int jc1 = min(j + 1, n - 1), jc2 = min(j + 2, n - 1), jc3 = min(j + 3, n - 1);
  float l0,t0,r0,b0,a0, l1,t1,r1,b1,a1, l2,t2,r2,b2,a2, l3,t3,r3,b3,a3;
  conv_box(boxes[j],   l0,t0,r0,b0,a0);
  conv_box(boxes[jc1], l1,t1,r1,b1,a1);
  conv_box(boxes[jc2], l2,t2,r2,b2,a2);
  conv_box(boxes[jc3], l3,t3,r3,b3,a3);
  bool full = (j + 3) < n;
  for (int rr = 0; rr < rpb; ++rr) {
    int i = by * rpb + rr;
    if (i >= n) return;
    float li,ti,ri,bi,ai;
    conv_box(boxes[i], li,ti,ri,bi,ai);
    float4 o;
    o.x = iou_one(li,ti,ri,bi,ai, l0,t0,r0,b0,a0);
    o.y = iou_one(li,ti,ri,bi,ai, l1,t1,r1,b1,a1);
    o.z = iou_one(li,ti,ri,bi,ai, l2,t2,r2,b2,a2);
    o.w = iou_one(li,ti,ri,bi,ai, l3,t3,r3,b3,a3);
    size_t row = (size_t)i * n;
    if (full) {
      // write-only 400MB stream: nontemporal keeps L2/L3 for the mask data.
      // (native clang vector type — __builtin_nontemporal_store rejects
      // HIP_vector_type float4)
      f32x4 ov = { o.x, o.y, o.z, o.w };
      __builtin_nontemporal_store(ov, reinterpret_cast<f32x4*>(out + row + j));
    } else {
      out[row + j] = o.x;
      if (j + 1 < n) out[row + j + 1] = o.y;
      if (j + 2 < n) out[row + j + 2] = o.z;
    }
  }
}

__global__ void k_iou(const float4* __restrict__ boxes, float* __restrict__ out,
                      int n, int rpb) {
  iou_body(boxes, out, n, rpb, blockIdx.x, blockIdx.y);
}

// Fused mask + IoU (independent work, disjoint outputs): mask's compute
// hides inside the write-bound IoU stream; the serial scan then runs solo.
__global__ __launch_bounds__(256) void k_maskiou(
    const float* __restrict__ sl, const float* __restrict__ st,
    const float* __restrict__ sr, const float* __restrict__ sb,
    const float* __restrict__ sa,
    u64* __restrict__ mask, u64* __restrict__ diag,
    u64* __restrict__ band1, u64* __restrict__ band2,
    int wstride, const float4* __restrict__ boxes, float* __restrict__ out,
    int n, int rpb, int nbx, int nmask, int gx) {
  int id = blockIdx.x;
  if (id < nmask) {
    mask_body(sl, st, sr, sb, sa, mask, diag, band1, band2, n, wstride,
              id % nbx, id / nbx);
  } else {
    int iid = id - nmask;
    iou_body(boxes, out, n, rpb, iid % gx, iid / gx);
  }
}

extern "C" void kernel_launch(void* const* d_in, const int* in_sizes, int n_in,
                              void* d_out, int out_size, void* d_ws, size_t ws_size,
                              hipStream_t stream) {
  const float* boxes = (const float*)d_in[0];
  const float* scores = (const float*)d_in[1];
  int n = in_sizes[1];
  float* out = (float*)d_out;
  size_t NN = (size_t)n * (size_t)n;
  float* keep = out + NN;

  int words = (n + 63) >> 6;
  int wstride = (words + 3) & ~3;
  size_t need = (size_t)n * wstride * 8          // mask
              + (size_t)words * 64 * 8 * 3       // diag + band1 + band2
              + 256                              // align slack
              + (size_t)n * 4 * 7;               // sl,st,sr,sb,sa,sidx,rank
  bool use_ws = (ws_size >= need);

  char* base = use_ws ? (char*)d_ws : (char*)d_out;
  size_t off = 0;
  u64* mask  = (u64*)(base + off); off += (size_t)n * wstride * 8;
  u64* diag  = (u64*)(base + off); off += (size_t)words * 64 * 8;
  u64* band1 = (u64*)(base + off); off += (size_t)words * 64 * 8;
  u64* band2 = (u64*)(base + off); off += (size_t)words * 64 * 8;
  off = (off + 255) & ~(size_t)255;
  float* sl  = (float*)(base + off); off += (size_t)n * 4;
  float* st_ = (float*)(base + off); off += (size_t)n * 4;
  float* sr  = (float*)(base + off); off += (size_t)n * 4;
  float* sb  = (float*)(base + off); off += (size_t)n * 4;
  float* sa  = (float*)(base + off); off += (size_t)n * 4;
  int* sidx  = (int*)(base + off); off += (size_t)n * 4;
  int* rank  = (int*)(base + off); off += (size_t)n * 4;

  int nb = (n + 255) / 256;
  k_zero<<<nb, 256, 0, stream>>>(rank, n);

  int jblocks = 40;
  int jchunk = (n + jblocks - 1) / jblocks;
  k_rank<<<dim3(nb, jblocks), 256, 0, stream>>>(scores, rank, n, jchunk);

  k_scatter<<<nb, 256, 0, stream>>>((const float4*)boxes, rank, sl, st_, sr, sb, sa, sidx, n);

  int rpb = 10;
  int nj4 = (n + 3) >> 2;
  int gx = (nj4 + 255) / 256;
  int gy = (n + rpb - 1) / rpb;

  if (use_ws) {
    int nmask = nb * words;
    int total = nmask + gx * gy;
    k_maskiou<<<total, 256, 0, stream>>>(sl, st_, sr, sb, sa, mask, diag, band1,
                                         band2, wstride, (const float4*)boxes,
                                         out, n, rpb, nb, nmask, gx);
    k_scan2<<<1, 256, 0, stream>>>(mask, diag, band1, band2, sidx, keep, n, wstride);
  } else {
    // scratch lives in front of out: must finish scan before iou overwrites it
    k_mask<<<dim3(nb, words), 256, 0, stream>>>(sl, st_, sr, sb, sa, mask, diag,
                                                band1, band2, n, wstride);
    k_scan2<<<1, 256, 0, stream>>>(mask, diag, band1, band2, sidx, keep, n, wstride);
    k_iou<<<dim3(gx, gy), 256, 0, stream>>>((const float4*)boxes, out, n, rpb);
  }
}

// Round 11
// 455.911 us; speedup vs baseline: 1.0103x; 1.0103x over previous
//
#include <hip/hip_runtime.h>

typedef unsigned long long u64;
typedef float f32x4 __attribute__((ext_vector_type(4)));

#define THR 0.5f

__device__ __forceinline__ u64 rfl64(u64 v) {
  unsigned lo = (unsigned)__builtin_amdgcn_readfirstlane((int)(unsigned)v);
  unsigned hi = (unsigned)__builtin_amdgcn_readfirstlane((int)(unsigned)(v >> 32));
  return ((u64)hi << 32) | lo;
}

// Convert one cxcywh box to ltrb + area, with FP contraction OFF so every op
// matches numpy's rn-per-op semantics bit-exactly (needed for the NMS >= 0.5
// predicate; a fused cx - 0.5*w -> fma differs in the last ulp).
__device__ __forceinline__ void conv_box(const float4 b, float& l, float& t,
                                         float& r, float& bo, float& a) {
  #pragma clang fp contract(off)
  float hw = 0.5f * b.z;
  float hh = 0.5f * b.w;
  l = b.x - hw;
  t = b.y - hh;
  r = b.x + hw;
  bo = b.y + hh;
  a = (r - l) * (bo - t);
}

__global__ void k_zero(int* __restrict__ rank, int n) {
  int i = blockIdx.x * blockDim.x + threadIdx.x;
  if (i < n) rank[i] = 0;
}

// Stable descending rank == stable argsort(-scores) position. j-chunked over
// blockIdx.y for parallelism.
__global__ void k_rank(const float* __restrict__ scores, int* __restrict__ rank,
                       int n, int jchunk) {
  int i = blockIdx.x * blockDim.x + threadIdx.x;
  if (i >= n) return;
  float si = scores[i];
  int j0 = blockIdx.y * jchunk;
  int j1 = min(j0 + jchunk, n);
  int c = 0;
  for (int j = j0; j < j1; ++j) {
    float sj = scores[j];
    c += ((sj > si) || (sj == si && j < i)) ? 1 : 0;
  }
  if (c) atomicAdd(rank + i, c);
}

__global__ void k_scatter(const float4* __restrict__ boxes, const int* __restrict__ rank,
                          float* __restrict__ sl, float* __restrict__ st,
                          float* __restrict__ sr, float* __restrict__ sb,
                          float* __restrict__ sa, int* __restrict__ sidx, int n) {
  int i = blockIdx.x * blockDim.x + threadIdx.x;
  if (i >= n) return;
  float l, t, r, b, a;
  conv_box(boxes[i], l, t, r, b, a);
  int k = rank[i];
  sl[k] = l; st[k] = t; sr[k] = r; sb[k] = b; sa[k] = a; sidx[k] = i;
}

// mask[k][w] bit b (j = w*64+b) set iff j>k, j<n, iou_nms(k,j) >= 0.5.
// Emits diag + band1/band2 (1st/2nd superdiagonal words) for the scan.
// Reference does NOT clamp the intersection on the NMS path — replicate.
__device__ __forceinline__ void mask_body(
    const float* __restrict__ sl, const float* __restrict__ st,
    const float* __restrict__ sr, const float* __restrict__ sb,
    const float* __restrict__ sa,
    u64* __restrict__ mask, u64* __restrict__ diag,
    u64* __restrict__ band1, u64* __restrict__ band2,
    int n, int wstride, int bx, int by) {
  #pragma clang fp contract(off)
  int k = bx * 256 + threadIdx.x;
  if (k >= n) return;
  int w = by;
  int jbase = w << 6;
  u64 word = 0;
  if (jbase + 63 > k) {
    float l = sl[k], t = st[k], r = sr[k], b = sb[k], a = sa[k];
    int jend = min(jbase + 64, n);
    for (int j = max(jbase, k + 1); j < jend; ++j) {
      float lmax = fmaxf(l, sl[j]);
      float tmax = fmaxf(t, st[j]);
      float rmin = fminf(r, sr[j]);
      float bmin = fminf(b, sb[j]);
      float wd = rmin - lmax;
      float hd = bmin - tmax;
      float inter = wd * hd;               // no clamp (matches reference NMS path)
      float denom = (a + sa[j]) - inter;
      float q = inter / denom;             // IEEE f32 div
      if (q >= THR) word |= 1ull << (j - jbase);
    }
  }
  mask[(size_t)k * wstride + w] = word;
  int kg = k >> 6;
  if (kg == w) diag[k] = word;
  if (w == kg + 1) band1[k] = word;
  if (w == kg + 2) band2[k] = word;
}

__global__ void k_mask(const float* __restrict__ sl, const float* __restrict__ st,
                       const float* __restrict__ sr, const float* __restrict__ sb,
                       const float* __restrict__ sa,
                       u64* __restrict__ mask, u64* __restrict__ diag,
                       u64* __restrict__ band1, u64* __restrict__ band2,
                       int n, int wstride) {
  mask_body(sl, st, sr, sb, sa, mask, diag, band1, band2, n, wstride,
            blockIdx.x, blockIdx.y);
}

// Canonical GCN wave64 OR-reduce via DPP; result uniform (readlane).
__device__ __forceinline__ u64 wave_or_u64(u64 v) {
  unsigned lo = (unsigned)v, hi = (unsigned)(v >> 32);
#define DPP_OR(x, ctrl, rmask) \
  x |= (unsigned)__builtin_amdgcn_update_dpp(0, (int)(x), ctrl, rmask, 0xF, true)
  DPP_OR(lo, 0x111, 0xF); DPP_OR(hi, 0x111, 0xF);   // row_shr:1
  DPP_OR(lo, 0x112, 0xF); DPP_OR(hi, 0x112, 0xF);   // row_shr:2
  DPP_OR(lo, 0x114, 0xF); DPP_OR(hi, 0x114, 0xF);   // row_shr:4
  DPP_OR(lo, 0x118, 0xF); DPP_OR(hi, 0x118, 0xF);   // row_shr:8
  DPP_OR(lo, 0x142, 0xA); DPP_OR(hi, 0x142, 0xA);   // row_bcast:15 rows 1,3
  DPP_OR(lo, 0x143, 0xC); DPP_OR(hi, 0x143, 0xC);   // row_bcast:31 rows 2,3
#undef DPP_OR
  unsigned flo = (unsigned)__builtin_amdgcn_readlane((int)lo, 63);
  unsigned fhi = (unsigned)__builtin_amdgcn_readlane((int)hi, 63);
  return ((u64)fhi << 32) | flo;
}

// ---------------------------------------------------------------------------
// Greedy serial NMS scan — 256 threads, runs SOLO.
//  wave 0: the 64-step recurrence is WAVE-UNIFORM, so it runs on the SALU:
//    scalar seed (readfirstlane), diag block loaded via uniform scalar loads
//    (SMEM, 3-buffer A/B/C rotation, 2 chunks lookahead, next group's chunks
//    0-1 issued before the barrier), branchless s_cselect steps. Round-10
//    bug: vector `if` per STEP = 64 exec-mask branches ≈ 2000+cy/group.
//  waves 1-3: fold of group g-2's kept rows into rem[w], w>g (unchanged).
// ---------------------------------------------------------------------------
__device__ __forceinline__ void scan_body9(
    const u64* __restrict__ mask, const u64* __restrict__ diag,
    const u64* __restrict__ band1, const u64* __restrict__ band2,
    const int* __restrict__ sidx, float* __restrict__ keep,
    int n, int wstride,
    u64* rem, u64* bsh1, u64* bsh2, u64* kwords,
    int (*kept)[64], int* nk_sh) {
  int t = threadIdx.x, wv = t >> 6, lane = t & 63;
  int ng = (n + 63) >> 6;
  rem[t] = 0;
  if (t < 3) nk_sh[t] = 0;
  u64 R1 = 0, R2 = 0;
  u64 A0=0,A1=0,A2=0,A3=0,A4=0,A5=0,A6=0,A7=0;
  u64 B0=0,B1=0,B2=0,B3=0,B4=0,B5=0,B6=0,B7=0;
  u64 C0=0,C1=0,C2=0,C3=0,C4=0,C5=0,C6=0,C7=0;
  if (wv == 0) {
    bsh1[lane] = band1[lane];
    bsh2[lane] = band2[lane];
    // preload group 0 chunks 0,1 (uniform -> scalar loads)
    A0=diag[0];A1=diag[1];A2=diag[2];A3=diag[3];
    A4=diag[4];A5=diag[5];A6=diag[6];A7=diag[7];
    B0=diag[8];B1=diag[9];B2=diag[10];B3=diag[11];
    B4=diag[12];B5=diag[13];B6=diag[14];B7=diag[15];
  }
  __syncthreads();
  for (int g = 0; g < ng; ++g) {
    int base = g << 6;
    if (wv == 0) {
      // vector prefetch of next group's bands (off the scalar chain)
      int nxt = base + 64 + lane;
      bool hn = (g + 1 < ng);
      u64 b1next = hn ? band1[nxt] : 0;
      u64 b2next = hn ? band2[nxt] : 0;
      u64 b1v = bsh1[lane], b2v = bsh2[lane];
      u64 s = rfl64(rem[g]) | R1;      // scalar seed
      int valid = n - base;
      if (valid < 64) s |= (~0ull) << valid;
      u64 kw = 0;
      const u64* __restrict__ dgrp = diag + base;   // uniform pointer
#define SLOAD(P0,P1,P2,P3,P4,P5,P6,P7, OFF) { \
      P0 = dgrp[(OFF)+0]; P1 = dgrp[(OFF)+1]; P2 = dgrp[(OFF)+2]; P3 = dgrp[(OFF)+3]; \
      P4 = dgrp[(OFF)+4]; P5 = dgrp[(OFF)+5]; P6 = dgrp[(OFF)+6]; P7 = dgrp[(OFF)+7]; }
#define SSTEP(BB, EQ) { u64 sup = (s >> (BB)) & 1ull; \
      kw |= (sup ^ 1ull) << (BB); s |= sup ? 0ull : (EQ); }
#define SCHUNK(B0v, E0,E1,E2,E3,E4,E5,E6,E7) \
      if (((~s >> (B0v)) & 0xFFull) != 0ull) { \
        SSTEP(B0v+0, E0) SSTEP(B0v+1, E1) SSTEP(B0v+2, E2) SSTEP(B0v+3, E3) \
        SSTEP(B0v+4, E4) SSTEP(B0v+5, E5) SSTEP(B0v+6, E6) SSTEP(B0v+7, E7) }
      SLOAD(C0,C1,C2,C3,C4,C5,C6,C7, 16); SCHUNK(0,  A0,A1,A2,A3,A4,A5,A6,A7);
      SLOAD(A0,A1,A2,A3,A4,A5,A6,A7, 24); SCHUNK(8,  B0,B1,B2,B3,B4,B5,B6,B7);
      SLOAD(B0,B1,B2,B3,B4,B5,B6,B7, 32); SCHUNK(16, C0,C1,C2,C3,C4,C5,C6,C7);
      SLOAD(C0,C1,C2,C3,C4,C5,C6,C7, 40); SCHUNK(24, A0,A1,A2,A3,A4,A5,A6,A7);
      SLOAD(A0,A1,A2,A3,A4,A5,A6,A7, 48); SCHUNK(32, B0,B1,B2,B3,B4,B5,B6,B7);
      SLOAD(B0,B1,B2,B3,B4,B5,B6,B7, 56); SCHUNK(40, C0,C1,C2,C3,C4,C5,C6,C7);
                                          SCHUNK(48, A0,A1,A2,A3,A4,A5,A6,A7);
                                          SCHUNK(56, B0,B1,B2,B3,B4,B5,B6,B7);
      // prefetch next group's chunks 0,1 (diag padded +64 -> safe at last g)
      SLOAD(A0,A1,A2,A3,A4,A5,A6,A7, 64);
      SLOAD(B0,B1,B2,B3,B4,B5,B6,B7, 72);
#undef SCHUNK
#undef SSTEP
#undef SLOAD
      if (lane == 0) kwords[g] = kw;
      u64 c1 = 0, c2 = 0;
      if (kw) {
        int nk = __popcll(kw);
        if ((kw >> lane) & 1ull) {
          int pos = __popcll(kw & ((1ull << lane) - 1ull));
          kept[g % 3][pos] = lane;
        }
        int npad = (nk + 31) & ~31;
        if (lane >= nk && lane < npad) kept[g % 3][lane] = 0;
        if (lane == 0) nk_sh[g % 3] = nk;
        u64 m = (u64)0 - ((kw >> lane) & 1ull);
        c1 = wave_or_u64(b1v & m);
        c2 = wave_or_u64(b2v & m);
      } else {
        if (lane == 0) nk_sh[g % 3] = 0;
      }
      R1 = R2 | c1;
      R2 = c2;
      bsh1[lane] = b1next;
      bsh2[lane] = b2next;
    } else {
      // fold group g-2's kept rows into rem[w], w > g (words w-h<=2 covered
      // by the R1/R2 band). 32 named loads in flight per batch.
      int w = t - 64;
      int gp = g - 2;
      if (gp >= 0 && w > g && w < ng) {
        int nkp = nk_sh[gp % 3];
        if (nkp) {
          const int* kp = kept[gp % 3];
          int basep = gp << 6;
          u64 acc = 0;
          for (int i = 0; i < nkp; i += 32) {
#define LD1(q) u64 v##q = mask[(size_t)(basep + kp[i + q]) * wstride + w];
            LD1(0)  LD1(1)  LD1(2)  LD1(3)  LD1(4)  LD1(5)  LD1(6)  LD1(7)
            LD1(8)  LD1(9)  LD1(10) LD1(11) LD1(12) LD1(13) LD1(14) LD1(15)
            LD1(16) LD1(17) LD1(18) LD1(19) LD1(20) LD1(21) LD1(22) LD1(23)
            LD1(24) LD1(25) LD1(26) LD1(27) LD1(28) LD1(29) LD1(30) LD1(31)
#undef LD1
#define ACC(q) if (i + q < nkp) acc |= v##q;
            ACC(0)  ACC(1)  ACC(2)  ACC(3)  ACC(4)  ACC(5)  ACC(6)  ACC(7)
            ACC(8)  ACC(9)  ACC(10) ACC(11) ACC(12) ACC(13) ACC(14) ACC(15)
            ACC(16) ACC(17) ACC(18) ACC(19) ACC(20) ACC(21) ACC(22) ACC(23)
            ACC(24) ACC(25) ACC(26) ACC(27) ACC(28) ACC(29) ACC(30) ACC(31)
#undef ACC
          }
          rem[w] |= acc;
        }
      }
    }
    __syncthreads();
  }
  // final scatter: sorted keep bits -> original order
  for (int k = t; k < n; k += 256) {
    u64 kwv = kwords[k >> 6];
    keep[sidx[k]] = ((kwv >> (k & 63)) & 1ull) ? 1.0f : 0.0f;
  }
}

__global__ __launch_bounds__(256, 1) void k_scan2(const u64* __restrict__ mask,
                                                  const u64* __restrict__ diag,
                                                  const u64* __restrict__ band1,
                                                  const u64* __restrict__ band2,
                                                  const int* __restrict__ sidx,
                                                  float* __restrict__ keep,
                                                  int n, int wstride) {
  __shared__ u64 rem[256];
  __shared__ u64 bsh1[64];
  __shared__ u64 bsh2[64];
  __shared__ u64 kwords[160];
  __shared__ int kept[3][64];
  __shared__ int nk_sh[3];
  scan_body9(mask, diag, band1, band2, sidx, keep, n, wstride,
             rem, bsh1, bsh2, kwords, kept, nk_sh);
}

// Pairwise IoU, original order, WITH clamp. Loose 2e-2 threshold -> fast rcp.
__device__ __forceinline__ float iou_one(float li, float ti, float ri, float bi, float ai,
                                         float lj, float tj, float rj, float bj, float aj) {
  float lmax = fmaxf(li, lj);
  float tmax = fmaxf(ti, tj);
  float rmin = fminf(ri, rj);
  float bmin = fminf(bi, bj);
  float w = fmaxf(rmin - lmax, 0.0f);
  float h = fmaxf(bmin - tmax, 0.0f);
  float inter = w * h;
  float denom = (ai + aj) - inter;
  return inter * __builtin_amdgcn_rcpf(denom);
}

__device__ __forceinline__ void iou_body(const float4* __restrict__ boxes,
                                         float* __restrict__ out,
                                         int n, int rpb, int bx, int by) {
  int nj4 = (n + 3) >> 2;
  int j4 = bx * 256 + threadIdx.x;
  if (j4 >= nj4) return;
  int j = j4 << 2;
  int jc1 = min(j + 1, n - 1), jc2 = min(j + 2, n - 1), jc3 = min(j + 3, n - 1);
  float l0,t0,r0,b0,a0, l1,t1,r1,b1,a1, l2,t2,r2,b2,a2, l3,t3,r3,b3,a3;
  conv_box(boxes[j],   l0,t0,r0,b0,a0);
  conv_box(boxes[jc1], l1,t1,r1,b1,a1);
  conv_box(boxes[jc2], l2,t2,r2,b2,a2);
  conv_box(boxes[jc3], l3,t3,r3,b3,a3);
  bool full = (j + 3) < n;
  for (int rr = 0; rr < rpb; ++rr) {
    int i = by * rpb + rr;
    if (i >= n) return;
    float li,ti,ri,bi,ai;
    conv_box(boxes[i], li,ti,ri,bi,ai);
    float4 o;
    o.x = iou_one(li,ti,ri,bi,ai, l0,t0,r0,b0,a0);
    o.y = iou_one(li,ti,ri,bi,ai, l1,t1,r1,b1,a1);
    o.z = iou_one(li,ti,ri,bi,ai, l2,t2,r2,b2,a2);
    o.w = iou_one(li,ti,ri,bi,ai, l3,t3,r3,b3,a3);
    size_t row = (size_t)i * n;
    if (full) {
      // write-only 400MB stream: nontemporal keeps L2/L3 for the mask data
      f32x4 ov = { o.x, o.y, o.z, o.w };
      __builtin_nontemporal_store(ov, reinterpret_cast<f32x4*>(out + row + j));
    } else {
      out[row + j] = o.x;
      if (j + 1 < n) out[row + j + 1] = o.y;
      if (j + 2 < n) out[row + j + 2] = o.z;
    }
  }
}

__global__ void k_iou(const float4* __restrict__ boxes, float* __restrict__ out,
                      int n, int rpb) {
  iou_body(boxes, out, n, rpb, blockIdx.x, blockIdx.y);
}

// Fused mask + IoU (independent work, disjoint outputs): mask's compute
// hides inside the write-bound IoU stream; the serial scan then runs solo.
__global__ __launch_bounds__(256) void k_maskiou(
    const float* __restrict__ sl, const float* __restrict__ st,
    const float* __restrict__ sr, const float* __restrict__ sb,
    const float* __restrict__ sa,
    u64* __restrict__ mask, u64* __restrict__ diag,
    u64* __restrict__ band1, u64* __restrict__ band2,
    int wstride, const float4* __restrict__ boxes, float* __restrict__ out,
    int n, int rpb, int nbx, int nmask, int gx) {
  int id = blockIdx.x;
  if (id < nmask) {
    mask_body(sl, st, sr, sb, sa, mask, diag, band1, band2, n, wstride,
              id % nbx, id / nbx);
  } else {
    int iid = id - nmask;
    iou_body(boxes, out, n, rpb, iid % gx, iid / gx);
  }
}

extern "C" void kernel_launch(void* const* d_in, const int* in_sizes, int n_in,
                              void* d_out, int out_size, void* d_ws, size_t ws_size,
                              hipStream_t stream) {
  const float* boxes = (const float*)d_in[0];
  const float* scores = (const float*)d_in[1];
  int n = in_sizes[1];
  float* out = (float*)d_out;
  size_t NN = (size_t)n * (size_t)n;
  float* keep = out + NN;

  int words = (n + 63) >> 6;
  int wstride = (words + 3) & ~3;
  size_t need = (size_t)n * wstride * 8            // mask
              + ((size_t)words * 64 + 64) * 8      // diag (+64 prefetch slack)
              + (size_t)words * 64 * 8 * 2         // band1 + band2
              + 256                                // align slack
              + (size_t)n * 4 * 7;                 // sl,st,sr,sb,sa,sidx,rank
  bool use_ws = (ws_size >= need);

  char* base = use_ws ? (char*)d_ws : (char*)d_out;
  size_t off = 0;
  u64* mask  = (u64*)(base + off); off += (size_t)n * wstride * 8;
  u64* diag  = (u64*)(base + off); off += ((size_t)words * 64 + 64) * 8;
  u64* band1 = (u64*)(base + off); off += (size_t)words * 64 * 8;
  u64* band2 = (u64*)(base + off); off += (size_t)words * 64 * 8;
  off = (off + 255) & ~(size_t)255;
  float* sl  = (float*)(base + off); off += (size_t)n * 4;
  float* st_ = (float*)(base + off); off += (size_t)n * 4;
  float* sr  = (float*)(base + off); off += (size_t)n * 4;
  float* sb  = (float*)(base + off); off += (size_t)n * 4;
  float* sa  = (float*)(base + off); off += (size_t)n * 4;
  int* sidx  = (int*)(base + off); off += (size_t)n * 4;
  int* rank  = (int*)(base + off); off += (size_t)n * 4;

  int nb = (n + 255) / 256;
  k_zero<<<nb, 256, 0, stream>>>(rank, n);

  int jblocks = 40;
  int jchunk = (n + jblocks - 1) / jblocks;
  k_rank<<<dim3(nb, jblocks), 256, 0, stream>>>(scores, rank, n, jchunk);

  k_scatter<<<nb, 256, 0, stream>>>((const float4*)boxes, rank, sl, st_, sr, sb, sa, sidx, n);

  int rpb = 10;
  int nj4 = (n + 3) >> 2;
  int gx = (nj4 + 255) / 256;
  int gy = (n + rpb - 1) / rpb;

  if (use_ws) {
    int nmask = nb * words;
    int total = nmask + gx * gy;
    k_maskiou<<<total, 256, 0, stream>>>(sl, st_, sr, sb, sa, mask, diag, band1,
                                         band2, wstride, (const float4*)boxes,
                                         out, n, rpb, nb, nmask, gx);
    k_scan2<<<1, 256, 0, stream>>>(mask, diag, band1, band2, sidx, keep, n, wstride);
  } else {
    // scratch lives in front of out: must finish scan before iou overwrites it
    k_mask<<<dim3(nb, words), 256, 0, stream>>>(sl, st_, sr, sb, sa, mask, diag,
                                                band1, band2, n, wstride);
    k_scan2<<<1, 256, 0, stream>>>(mask, diag, band1, band2, sidx, keep, n, wstride);
    k_iou<<<dim3(gx, gy), 256, 0, stream>>>((const float4*)boxes, out, n, rpb);
  }
}